// Round 7
// baseline (174.732 us; speedup 1.0000x reference)
//
#include <hip/hip_runtime.h>
#include <math.h>

#define T_LEN 4096   // time length (FFT size)
#define N2    2048   // packed complex FFT size
#define TOPK  7      // int(ln(2047)) = 7
#define NCH   256    // channels (d)
#define R8F 0.70710678f              // sqrt(2)/2 in f32

// LDS slot map for interleaved complex storage (fft kernel).
// AD(a) = a + (a>>3) + (a>>8): conflict-floor access for every phase pattern.
#define AD(a) ((a) + ((a) >> 3) + ((a) >> 8))

// native clang vector type: required by __builtin_nontemporal_load/store.
typedef float nt_f4 __attribute__((ext_vector_type(4)));

// complex f32 helpers structured for v_pk_add_f32 / v_pk_fma_f32 SLP packing.
typedef float2 c32;
__device__ __forceinline__ c32 cadd(c32 a, c32 b) { return make_float2(a.x + b.x, a.y + b.y); }
__device__ __forceinline__ c32 csub(c32 a, c32 b) { return make_float2(a.x - b.x, a.y - b.y); }
__device__ __forceinline__ c32 cmul(c32 a, c32 w) {
    return make_float2(w.x * a.x - w.y * a.y, w.x * a.y + w.y * a.x);
}
__device__ __forceinline__ c32 csq(c32 a) {
    return make_float2(a.x * a.x - a.y * a.y, 2.0f * a.x * a.y);
}
__device__ __forceinline__ c32 mulnegi(c32 a) { return make_float2(a.y, -a.x); }  // a * (-i)

// DIF radix-8 butterfly on c32 registers; twiddles as in-register powers of w1.
__device__ __forceinline__ void dft8_pw(c32 x[8], c32 w1)
{
    c32 t0 = cadd(x[0], x[4]), t4 = csub(x[0], x[4]);
    c32 t1 = cadd(x[1], x[5]), t5 = csub(x[1], x[5]);
    c32 t2 = cadd(x[2], x[6]), t6 = csub(x[2], x[6]);
    c32 t3 = cadd(x[3], x[7]), t7 = csub(x[3], x[7]);
    c32 s0 = cadd(t0, t2), s2 = csub(t0, t2);
    c32 s1 = cadd(t1, t3), s3 = csub(t1, t3);
    x[0] = cadd(s0, s1);
    x[4] = csub(s0, s1);
    c32 s3n = mulnegi(s3);
    x[2] = cadd(s2, s3n);                  // s2 - i*s3
    x[6] = csub(s2, s3n);                  // s2 + i*s3
    c32 c1 = make_float2(R8F * (t5.x + t5.y), R8F * (t5.y - t5.x));
    c32 c2 = mulnegi(t6);
    c32 c3 = make_float2(R8F * (t7.y - t7.x), -R8F * (t7.x + t7.y));
    c32 d0 = cadd(t4, c2), d1 = csub(t4, c2);
    c32 d2 = cadd(c1, c3), d3 = csub(c1, c3);
    x[1] = cadd(d0, d2);
    x[5] = csub(d0, d2);
    c32 d3n = mulnegi(d3);
    x[3] = cadd(d1, d3n);                  // d1 - i*d3
    x[7] = csub(d1, d3n);                  // d1 + i*d3

    c32 w2 = csq(w1);
    c32 w3 = cmul(w1, w2);
    c32 w4 = csq(w2);
    c32 w5 = cmul(w3, w2);
    c32 w6 = csq(w3);
    c32 w7 = cmul(w4, w3);
    x[1] = cmul(x[1], w1);
    x[2] = cmul(x[2], w2);
    x[3] = cmul(x[3], w3);
    x[4] = cmul(x[4], w4);
    x[5] = cmul(x[5], w5);
    x[6] = cmul(x[6], w6);
    x[7] = cmul(x[7], w7);
}

// ---------------- K0: twiddle tables + transpose FUSED WITH FFT PHASE 1 ------
// blocks [0,16): tw[p] (f64) / twf[p] (f32) = e^{-2*pi*i*p/4096}.
// blocks [16, 16+2048): block (b, c-tile-32, j-tile-16) loads the exact rows
// phase 1 needs (t = 2*j0 + 512u + rr, 8 chunks of 32 consecutive rows x 32
// channels, line-coalesced), runs the radix-8 stride-256 pass per (c, j), and
// writes phase-1 output gz[bc][m*256 + j] (128 B runs, coalesced). The FFT
// kernel then starts at phase 2. Phase-1 compute (~3 us) hides under the
// transpose's 128 MB of bandwidth (~22 us).
// w1 via f64 sincos per thread (bit-identical to the twf table; twf itself is
// written by racing sibling blocks, so it must not be read here).
// LDS tile column-XOR-swizzled: swz(lr) = ((lr&7)^((lr>>3)&7))<<2 keeps the
// float4 write conflict-free (8 consecutive rows -> 8 distinct swizzles) and
// the (cc, dj)-gather at <=2-way (free).
__global__ __launch_bounds__(256) void prep_kernel(
    const float* __restrict__ x, float2* __restrict__ gz,
    double2* __restrict__ tw, float2* __restrict__ twf)
{
    if (blockIdx.x < 16) {
        int p = blockIdx.x * 256 + threadIdx.x;
        double th = -2.0 * 3.14159265358979323846 * (double)p / (double)T_LEN;
        double c = cos(th), s = sin(th);
        tw[p]  = make_double2(c, s);
        twf[p] = make_float2((float)c, (float)s);
        return;
    }
    __shared__ float tile[256][32];       // 32 KB
    const int bid = blockIdx.x - 16;
    const int jt = bid & 15;              // j-tile: j in [16*jt, 16*jt+16)
    const int ct = (bid >> 4) & 7;        // c-tile: c in [32*ct, 32*ct+32)
    const int b  = bid >> 7;
    const int j0 = jt << 4, c0 = ct << 5;
    const int tid = threadIdx.x;

    // load: 256 rows (t = 2*j0 + 512u + rr, u=0..7, rr=0..31) x 32 channels
    const float* src = x + (size_t)b * T_LEN * NCH + c0;
#pragma unroll
    for (int s = 0; s < 8; ++s) {
        int fid = tid + (s << 8);
        int lr  = fid >> 3;               // 0..255
        int qc  = (fid & 7) << 2;         // 0,4,..,28
        int t   = (j0 << 1) + ((lr >> 5) << 9) + (lr & 31);
        nt_f4 v = __builtin_nontemporal_load(
            (const nt_f4*)(src + (size_t)t * NCH + qc));
        int sc = qc ^ ((((lr & 7) ^ ((lr >> 3) & 7))) << 2);
        *(nt_f4*)&tile[lr][sc] = v;       // 16B-aligned (sc multiple of 4)
    }
    __syncthreads();

    // compute: thread handles ONE j (dj = tid&15) and TWO channels (h=0,1).
    const int dj = tid & 15;
    const int j  = j0 + dj;
    double th = -3.14159265358979323846 * (double)j / 1024.0;  // -2pi*(2j)/4096
    c32 w1 = make_float2((float)cos(th), (float)sin(th));

    for (int h = 0; h < 2; ++h) {
        const int cc = (tid >> 4) + (h << 4);   // 0..31
        c32 xx[8];
#pragma unroll
        for (int u = 0; u < 8; ++u) {
            int lr0 = (u << 5) + (dj << 1);     // y[j+256u] = x[2j+512u] + i*x[..+1]
            int lr1 = lr0 + 1;
            int s0  = cc ^ ((((lr0 & 7) ^ ((lr0 >> 3) & 7))) << 2);
            int s1  = cc ^ ((((lr1 & 7) ^ ((lr1 >> 3) & 7))) << 2);
            xx[u] = make_float2(tile[lr0][s0], tile[lr1][s1]);
        }
        dft8_pw(xx, w1);                         // phase-1 twiddle base = 2j
        float2* gcol = gz + ((size_t)((b << 8) + c0 + cc)) * N2;
#pragma unroll
        for (int m = 0; m < 8; ++m)
            gcol[(m << 8) + j] = xx[m];          // dj-runs of 16 -> 128 B coalesced
    }
}

// pack (f32 magnitude^2 bits, bin) into one monotone u64 key.
__device__ __forceinline__ unsigned long long packkey32(float mag, int k) {
    return ((unsigned long long)__float_as_uint(mag) << 32)
         | (unsigned long long)(2047 - k);
}

// descending compare-swap for the per-thread sorting network
#define CSWAP(i, j) { unsigned long long a_ = keys[i], b_ = keys[j]; \
                      keys[i] = a_ > b_ ? a_ : b_; keys[j] = a_ > b_ ? b_ : a_; }

// ---------------- K1: radix-8 real FFT phases 2-4 (f32) + top-7 --------------
// One block per (b,c) column. Phase 1 was done by prep; phase 2 reads gz
// directly from global (256 B runs per half-wave, L3-resident), saving one
// LDS round-trip + one barrier + a third of the butterfly compute here.
__global__ __launch_bounds__(256, 8) void fft_topk_kernel(
    const float* __restrict__ xt, const double2* __restrict__ tw,
    const float2* __restrict__ twf,
    int* __restrict__ k_out, float4* __restrict__ ab4)
{
    __shared__ float2 zz[AD(N2 - 1) + 3];            // 2312 float2 = 18.5 KB
    __shared__ unsigned long long wavetop[4 * TOPK]; // 28 wave-level candidates
    __shared__ unsigned long long selkey[TOPK];

    const int tid = threadIdx.x;
    const int bc  = blockIdx.x;          // b*256 + c
    const float2* gcol = ((const float2*)xt) + (size_t)bc * N2;

    c32 x[8];
    // phase 2: sub-FFT size 256, j2 = tid&31, stride 32; tw base 16*j2.
    // Inputs come straight from gz (phase-1 output, coalesced global read).
    {
        const int g = tid >> 5, j2 = tid & 31, base = (g << 8) + j2;
#pragma unroll
        for (int u = 0; u < 8; ++u)
            x[u] = gcol[base + (u << 5)];
        dft8_pw(x, twf[16 * j2]);
#pragma unroll
        for (int m = 0; m < 8; ++m)
            zz[AD(base + (m << 5))] = x[m];
    }
    __syncthreads();

    // phase 3: sub-FFT size 32, j3 = tid&3, stride 4; tw base 128*j3.
    {
        const int g3 = tid >> 2, j3 = tid & 3, base = (g3 << 5) + j3;
#pragma unroll
        for (int u = 0; u < 8; ++u)
            x[u] = zz[AD(base + (u << 2))];
        dft8_pw(x, twf[128 * j3]);
#pragma unroll
        for (int m = 0; m < 8; ++m)
            zz[AD(base + (m << 2))] = x[m];
    }
    __syncthreads();

    // phase 4: read both stride-1 quads into registers (digit-index space),
    // barrier, DFT4 in registers, write natural-order at AD(k).
#pragma unroll
    for (int q = 0; q < 2; ++q) {
        int h4 = ((q << 8) + tid) << 2;
#pragma unroll
        for (int r = 0; r < 4; ++r)
            x[q * 4 + r] = zz[AD(h4 + r)];
    }
    __syncthreads();
#pragma unroll
    for (int q = 0; q < 2; ++q) {
        c32 b0 = x[q*4+0], b1 = x[q*4+1], b2 = x[q*4+2], b3 = x[q*4+3];
        c32 e0 = cadd(b0, b2), e1 = csub(b0, b2);
        c32 e2 = cadd(b1, b3), e3 = csub(b1, b3);
        c32 e3n = mulnegi(e3);
        // position p = 4*(q*256+tid)+r  <->  bin k = kbase + r*512
        int kbase = ((tid & 7) << 6) | (((tid >> 3) & 7) << 3) | (q << 2) | (tid >> 6);
        zz[AD(kbase)]        = cadd(e0, e2);
        zz[AD(kbase + 1024)] = csub(e0, e2);
        zz[AD(kbase +  512)] = cadd(e1, e3n);   // e1 - i*e3
        zz[AD(kbase + 1536)] = csub(e1, e3n);   // e1 + i*e3
    }
    __syncthreads();

    // conjugate-pair magnitudes: k in [1,1024]; |X[k]|^2 = |A+WB|^2,
    // |X[2048-k]|^2 = |A-WB|^2 from ONE read pair (Y[k], Y[2048-k]).
    unsigned long long keys[8];
#pragma unroll
    for (int j = 0; j < 4; ++j) {
        int k  = 1 + tid + (j << 8);      // 1..1024
        int kp = N2 - k;                  // 1024..2047
        float2 yk = zz[AD(k)];
        float2 yp = zz[AD(kp)];
        float Ar = 0.5f * (yk.x + yp.x), Ai = 0.5f * (yk.y - yp.y);
        float Br = 0.5f * (yk.y + yp.y), Bi = -0.5f * (yk.x - yp.x);
        float2 t = twf[k];                // lane-stride 8 B: coalesced
        float Cr = t.x * Br - t.y * Bi;
        float Ci = t.x * Bi + t.y * Br;
        float m1 = (Ar + Cr) * (Ar + Cr) + (Ai + Ci) * (Ai + Ci);
        float m2 = (Ar - Cr) * (Ar - Cr) + (Ai - Ci) * (Ai - Ci);
        keys[2 * j]     = packkey32(m1, k);
        keys[2 * j + 1] = (kp != k) ? packkey32(m2, kp) : 0ULL;
    }

    // ---- per-thread descending sort (Batcher 8-element network, 19 CEs)
    CSWAP(0,1) CSWAP(2,3) CSWAP(4,5) CSWAP(6,7)
    CSWAP(0,2) CSWAP(1,3) CSWAP(4,6) CSWAP(5,7)
    CSWAP(1,2) CSWAP(5,6)
    CSWAP(0,4) CSWAP(1,5) CSWAP(2,6) CSWAP(3,7)
    CSWAP(2,4) CSWAP(3,5)
    CSWAP(1,2) CSWAP(3,4) CSWAP(5,6)

    const int wv = tid >> 6, ln = tid & 63;
    unsigned long long lb = keys[0];

    // level 1: per-wave top-7; 32-bit max-butterfly on the mag word + ballot
    // winner-resolve; exact-mag ties fall to a rare uniform branch.
    for (int it = 0; it < TOPK; ++it) {
        unsigned int hl = (unsigned int)(lb >> 32);
        unsigned int h  = hl;
#pragma unroll
        for (int off = 32; off; off >>= 1) {
            unsigned int o = __shfl_xor(h, off);
            h = (o > h) ? o : h;
        }
        unsigned long long mask = __ballot(hl == h);
        unsigned long long v;
        if (__popcll(mask) == 1) {
            int src = __ffsll((long long)mask) - 1;
            v = ((unsigned long long)h << 32)
              | (unsigned long long)__shfl((unsigned int)lb, src);
        } else {
            unsigned int l = (hl == h) ? (unsigned int)lb : 0u;
#pragma unroll
            for (int off = 32; off; off >>= 1) {
                unsigned int o = __shfl_xor(l, off);
                l = (o > l) ? o : l;
            }
            v = ((unsigned long long)h << 32) | l;
        }
        if (ln == 0) wavetop[wv * TOPK + it] = v;
        if (v == lb && v) {
            keys[0]=keys[1]; keys[1]=keys[2]; keys[2]=keys[3]; keys[3]=keys[4];
            keys[4]=keys[5]; keys[5]=keys[6]; keys[6]=keys[7]; keys[7]=0ULL;
            lb = keys[0];
        }
    }
    __syncthreads();

    // level 2: merge 28 candidates on one wave (offs <=16 keep lanes <32)
    if (tid < 32) {
        unsigned long long v = (tid < 4 * TOPK) ? wavetop[tid] : 0ULL;
        for (int it = 0; it < TOPK; ++it) {
            unsigned long long m = v;
#pragma unroll
            for (int off = 16; off; off >>= 1) {
                unsigned long long o = __shfl_xor(m, off);
                if (o > m) m = o;
            }
            if (tid == 0) selkey[it] = m;
            if (m == v) v = 0ULL;
        }
    }
    __syncthreads();

    // emit: out = a*cos(theta)+b*sin(theta), theta = 2*pi*k*n/T
    // a = 4*Re/T, b = -4*Im/T; wr + i*wi = e^{+i*2*pi*k/T}.
    if (tid < TOPK) {
        int k  = 2047 - (int)(selkey[tid] & 2047ULL);
        float2 ykf = zz[AD(k)];
        float2 ypf = zz[AD(N2 - k)];
        double ykx = (double)ykf.x, yky = (double)ykf.y;
        double ypx = (double)ypf.x, ypy = (double)ypf.y;
        double Ar = 0.5 * (ykx + ypx), Ai = 0.5 * (yky - ypy);
        double Br = 0.5 * (yky + ypy), Bi = -0.5 * (ykx - ypx);
        double2 t = tw[k];
        double Xr = Ar + t.x * Br - t.y * Bi;
        double Xi = Ai + t.x * Bi + t.y * Br;
        k_out[tid * 4096 + bc] = k;
        ab4[tid * 4096 + bc] = make_float4(
            (float)( 4.0 * Xr / (double)T_LEN),
            (float)(-4.0 * Xi / (double)T_LEN),
            (float)t.x, (float)(-t.y));
    }
}

// ---------------- K2: reconstruction via per-frequency rotators --------------
// block = 256 threads (one per channel), grid = 16 b * 128 n-chunks of 32.
// Output staged in LDS 16n x 256c subtiles -> contiguous nontemporal float4.
__global__ __launch_bounds__(256) void recon_kernel(
    const int* __restrict__ k_in, const float4* __restrict__ ab4,
    float* __restrict__ out)
{
    __shared__ float tile[16][256];

    const int tid   = threadIdx.x;        // channel c
    const int chunk = blockIdx.x & 127;
    const int b     = blockIdx.x >> 7;
    const int bc    = (b << 8) + tid;
    const int n0    = chunk << 5;         // 32 time steps per block

    const float c0 = 6.28318530717958647692f / 4096.0f;
    float aa[TOPK], bb[TOPK];
    c32 z[TOPK], w[TOPK];
#pragma unroll
    for (int j = 0; j < TOPK; ++j) {
        int k    = k_in[j * 4096 + bc];
        float4 v = ab4[j * 4096 + bc];
        aa[j] = v.x; bb[j] = v.y; w[j] = make_float2(v.z, v.w);
        int m0 = (k * n0) & (T_LEN - 1);      // exact integer phase reduction
        float ang = (float)m0 * c0;
        __sincosf(ang, &z[j].y, &z[j].x);
    }

    float* obase = out + ((size_t)b * T_LEN + n0) * NCH;
    for (int r = 0; r < 2; ++r) {             // 2 subtiles of 16 n
#pragma unroll
        for (int i = 0; i < 16; ++i) {
            float acc = 0.f;
#pragma unroll
            for (int j = 0; j < TOPK; ++j) {
                acc += aa[j] * z[j].x + bb[j] * z[j].y;
                z[j] = cmul(z[j], w[j]);
            }
            tile[i][tid] = acc;
        }
        __syncthreads();
        // 1024 float4s per subtile, 4 per thread, contiguous per wave
#pragma unroll
        for (int s = 0; s < 4; ++s) {
            int fid = tid + (s << 8);
            int ni  = fid >> 6;
            int c4  = (fid & 63) << 2;
            nt_f4 v = { tile[ni][c4], tile[ni][c4 + 1],
                        tile[ni][c4 + 2], tile[ni][c4 + 3] };
            __builtin_nontemporal_store(v,
                (nt_f4*)(obase + (size_t)((r << 4) + ni) * NCH + c4));
        }
        __syncthreads();
    }
}

// ---------------- launch -----------------------------------------------------
extern "C" void kernel_launch(void* const* d_in, const int* in_sizes, int n_in,
                              void* d_out, int out_size, void* d_ws, size_t ws_size,
                              hipStream_t stream) {
    const float* x   = (const float*)d_in[0];
    float*       out = (float*)d_out;
    char*        ws  = (char*)d_ws;

    // ws layout: [0, 65536)            tw   double2[4096]
    //            [65536, +114688)      k    int[7][4096]
    //            [180224, +458752)     ab4  float4[7][4096]
    //            [638976, +32768)      twf  float2[4096]
    double2* tw    = (double2*)(ws);
    int*     k_ws  = (int*)   (ws + 65536);
    float4*  ab_ws = (float4*)(ws + 180224);
    float2*  twf   = (float2*)(ws + 638976);

    // d_out doubles as the phase-1 spectrum scratch gz (exactly 64 MB:
    // 4096 cols x 2048 complex f32); recon_kernel overwrites every element
    // of it last, so validation sees only the output.
    prep_kernel     <<<16 + 2048, 256, 0, stream>>>(x, (float2*)out, tw, twf);
    fft_topk_kernel <<<4096, 256, 0, stream>>>(out, tw, twf, k_ws, ab_ws);
    recon_kernel    <<<2048, 256, 0, stream>>>(k_ws, ab_ws, out);
}

// Round 8
// 170.196 us; speedup vs baseline: 1.0266x; 1.0266x over previous
//
#include <hip/hip_runtime.h>
#include <math.h>

#define T_LEN 4096   // time length (FFT size)
#define N2    2048   // packed complex FFT size
#define TOPK  7      // int(ln(2047)) = 7
#define NCH   256    // channels (d)
#define R8F 0.70710678f              // sqrt(2)/2 in f32

// LDS slot map for interleaved complex storage (fft kernel).
// AD(a) = a + (a>>3) + (a>>8): conflict-floor access for every phase pattern.
#define AD(a) ((a) + ((a) >> 3) + ((a) >> 8))

// native clang vector type: required by __builtin_nontemporal_load/store.
typedef float nt_f4 __attribute__((ext_vector_type(4)));

// complex f32 helpers structured for v_pk_add_f32 / v_pk_fma_f32 SLP packing.
typedef float2 c32;
__device__ __forceinline__ c32 cadd(c32 a, c32 b) { return make_float2(a.x + b.x, a.y + b.y); }
__device__ __forceinline__ c32 csub(c32 a, c32 b) { return make_float2(a.x - b.x, a.y - b.y); }
__device__ __forceinline__ c32 cmul(c32 a, c32 w) {
    return make_float2(w.x * a.x - w.y * a.y, w.x * a.y + w.y * a.x);
}
__device__ __forceinline__ c32 csq(c32 a) {
    return make_float2(a.x * a.x - a.y * a.y, 2.0f * a.x * a.y);
}
__device__ __forceinline__ c32 mulnegi(c32 a) { return make_float2(a.y, -a.x); }  // a * (-i)

// DIF radix-8 butterfly on c32 registers; twiddles as in-register powers of w1.
__device__ __forceinline__ void dft8_pw(c32 x[8], c32 w1)
{
    c32 t0 = cadd(x[0], x[4]), t4 = csub(x[0], x[4]);
    c32 t1 = cadd(x[1], x[5]), t5 = csub(x[1], x[5]);
    c32 t2 = cadd(x[2], x[6]), t6 = csub(x[2], x[6]);
    c32 t3 = cadd(x[3], x[7]), t7 = csub(x[3], x[7]);
    c32 s0 = cadd(t0, t2), s2 = csub(t0, t2);
    c32 s1 = cadd(t1, t3), s3 = csub(t1, t3);
    x[0] = cadd(s0, s1);
    x[4] = csub(s0, s1);
    c32 s3n = mulnegi(s3);
    x[2] = cadd(s2, s3n);                  // s2 - i*s3
    x[6] = csub(s2, s3n);                  // s2 + i*s3
    c32 c1 = make_float2(R8F * (t5.x + t5.y), R8F * (t5.y - t5.x));
    c32 c2 = mulnegi(t6);
    c32 c3 = make_float2(R8F * (t7.y - t7.x), -R8F * (t7.x + t7.y));
    c32 d0 = cadd(t4, c2), d1 = csub(t4, c2);
    c32 d2 = cadd(c1, c3), d3 = csub(c1, c3);
    x[1] = cadd(d0, d2);
    x[5] = csub(d0, d2);
    c32 d3n = mulnegi(d3);
    x[3] = cadd(d1, d3n);                  // d1 - i*d3
    x[7] = csub(d1, d3n);                  // d1 + i*d3

    c32 w2 = csq(w1);
    c32 w3 = cmul(w1, w2);
    c32 w4 = csq(w2);
    c32 w5 = cmul(w3, w2);
    c32 w6 = csq(w3);
    c32 w7 = cmul(w4, w3);
    x[1] = cmul(x[1], w1);
    x[2] = cmul(x[2], w2);
    x[3] = cmul(x[3], w3);
    x[4] = cmul(x[4], w4);
    x[5] = cmul(x[5], w5);
    x[6] = cmul(x[6], w6);
    x[7] = cmul(x[7], w7);
}

// ---------------- K0: twiddle tables + transpose FUSED WITH FFT PHASE 1 ------
// blocks [0,16): tw[p] (f64) / twf[p] (f32) = e^{-2*pi*i*p/4096}.
// blocks [16, 16+2048): block (b, c-tile-32, j-tile-16) loads the exact rows
// phase 1 needs, runs the radix-8 stride-256 pass per (c, j), and writes
// phase-1 output gz[bc][m*256 + j] (128 B runs). The FFT kernel starts at
// phase 2. w1 via HARDWARE __sincosf (r7 post-mortem: the f64 sincos was a
// ~500-cycle software chain per wave = ~6-7 us across the grid, canceling the
// fusion win; f32 w1 error ~2 ulp -> ~1.5e-6 through the power chain, vs
// rank-7 selection gaps of ~1e-1 — no selection risk).
// LDS tile column-XOR-swizzled: swz(lr) = ((lr&7)^((lr>>3)&7))<<2 keeps the
// float4 write conflict-free and the (cc, dj)-gather at <=2-way (free).
__global__ __launch_bounds__(256) void prep_kernel(
    const float* __restrict__ x, float2* __restrict__ gz,
    double2* __restrict__ tw, float2* __restrict__ twf)
{
    if (blockIdx.x < 16) {
        int p = blockIdx.x * 256 + threadIdx.x;
        double th = -2.0 * 3.14159265358979323846 * (double)p / (double)T_LEN;
        double c = cos(th), s = sin(th);
        tw[p]  = make_double2(c, s);
        twf[p] = make_float2((float)c, (float)s);
        return;
    }
    __shared__ float tile[256][32];       // 32 KB
    const int bid = blockIdx.x - 16;
    const int jt = bid & 15;              // j-tile: j in [16*jt, 16*jt+16)
    const int ct = (bid >> 4) & 7;        // c-tile: c in [32*ct, 32*ct+32)
    const int b  = bid >> 7;
    const int j0 = jt << 4, c0 = ct << 5;
    const int tid = threadIdx.x;

    // load: 256 rows (t = 2*j0 + 512u + rr, u=0..7, rr=0..31) x 32 channels
    const float* src = x + (size_t)b * T_LEN * NCH + c0;
#pragma unroll
    for (int s = 0; s < 8; ++s) {
        int fid = tid + (s << 8);
        int lr  = fid >> 3;               // 0..255
        int qc  = (fid & 7) << 2;         // 0,4,..,28
        int t   = (j0 << 1) + ((lr >> 5) << 9) + (lr & 31);
        nt_f4 v = __builtin_nontemporal_load(
            (const nt_f4*)(src + (size_t)t * NCH + qc));
        int sc = qc ^ ((((lr & 7) ^ ((lr >> 3) & 7))) << 2);
        *(nt_f4*)&tile[lr][sc] = v;       // 16B-aligned (sc multiple of 4)
    }
    __syncthreads();

    // compute: thread handles ONE j (dj = tid&15) and TWO channels (h=0,1).
    const int dj = tid & 15;
    const int j  = j0 + dj;
    // w1 = e^{-i*pi*j/1024}; |ang| < 0.79 so f32 reduction is exact
    float ang = (float)j * -0.00306796157577128218f;   // -pi/1024
    float s1v, c1v;
    __sincosf(ang, &s1v, &c1v);
    c32 w1 = make_float2(c1v, s1v);

    for (int h = 0; h < 2; ++h) {
        const int cc = (tid >> 4) + (h << 4);   // 0..31
        c32 xx[8];
#pragma unroll
        for (int u = 0; u < 8; ++u) {
            int lr0 = (u << 5) + (dj << 1);     // y[j+256u] = x[2j+512u] + i*x[..+1]
            int lr1 = lr0 + 1;
            int s0  = cc ^ ((((lr0 & 7) ^ ((lr0 >> 3) & 7))) << 2);
            int s1  = cc ^ ((((lr1 & 7) ^ ((lr1 >> 3) & 7))) << 2);
            xx[u] = make_float2(tile[lr0][s0], tile[lr1][s1]);
        }
        dft8_pw(xx, w1);                         // phase-1 twiddle base = 2j
        float2* gcol = gz + ((size_t)((b << 8) + c0 + cc)) * N2;
#pragma unroll
        for (int m = 0; m < 8; ++m)
            gcol[(m << 8) + j] = xx[m];          // dj-runs of 16 -> 128 B coalesced
    }
}

// pack (f32 magnitude^2 bits, bin) into one monotone u64 key.
__device__ __forceinline__ unsigned long long packkey32(float mag, int k) {
    return ((unsigned long long)__float_as_uint(mag) << 32)
         | (unsigned long long)(2047 - k);
}

// descending compare-swap for the per-thread sorting network
#define CSWAP(i, j) { unsigned long long a_ = keys[i], b_ = keys[j]; \
                      keys[i] = a_ > b_ ? a_ : b_; keys[j] = a_ > b_ ? b_ : a_; }

// ---------------- K1: radix-8 real FFT phases 2-4 (f32) + top-7 --------------
// One block per (b,c) column. Phase 1 was done by prep; phase 2 reads gz
// directly from global (256 B runs per half-wave, L3-resident), saving one
// LDS round-trip + one barrier + a third of the butterfly compute here.
__global__ __launch_bounds__(256, 8) void fft_topk_kernel(
    const float* __restrict__ xt, const double2* __restrict__ tw,
    const float2* __restrict__ twf,
    int* __restrict__ k_out, float4* __restrict__ ab4)
{
    __shared__ float2 zz[AD(N2 - 1) + 3];            // 2312 float2 = 18.5 KB
    __shared__ unsigned long long wavetop[4 * TOPK]; // 28 wave-level candidates
    __shared__ unsigned long long selkey[TOPK];

    const int tid = threadIdx.x;
    const int bc  = blockIdx.x;          // b*256 + c
    const float2* gcol = ((const float2*)xt) + (size_t)bc * N2;

    c32 x[8];
    // phase 2: sub-FFT size 256, j2 = tid&31, stride 32; tw base 16*j2.
    // Inputs come straight from gz (phase-1 output, coalesced global read).
    {
        const int g = tid >> 5, j2 = tid & 31, base = (g << 8) + j2;
#pragma unroll
        for (int u = 0; u < 8; ++u)
            x[u] = gcol[base + (u << 5)];
        dft8_pw(x, twf[16 * j2]);
#pragma unroll
        for (int m = 0; m < 8; ++m)
            zz[AD(base + (m << 5))] = x[m];
    }
    __syncthreads();

    // phase 3: sub-FFT size 32, j3 = tid&3, stride 4; tw base 128*j3.
    {
        const int g3 = tid >> 2, j3 = tid & 3, base = (g3 << 5) + j3;
#pragma unroll
        for (int u = 0; u < 8; ++u)
            x[u] = zz[AD(base + (u << 2))];
        dft8_pw(x, twf[128 * j3]);
#pragma unroll
        for (int m = 0; m < 8; ++m)
            zz[AD(base + (m << 2))] = x[m];
    }
    __syncthreads();

    // phase 4: read both stride-1 quads into registers (digit-index space),
    // barrier, DFT4 in registers, write natural-order at AD(k).
#pragma unroll
    for (int q = 0; q < 2; ++q) {
        int h4 = ((q << 8) + tid) << 2;
#pragma unroll
        for (int r = 0; r < 4; ++r)
            x[q * 4 + r] = zz[AD(h4 + r)];
    }
    __syncthreads();
#pragma unroll
    for (int q = 0; q < 2; ++q) {
        c32 b0 = x[q*4+0], b1 = x[q*4+1], b2 = x[q*4+2], b3 = x[q*4+3];
        c32 e0 = cadd(b0, b2), e1 = csub(b0, b2);
        c32 e2 = cadd(b1, b3), e3 = csub(b1, b3);
        c32 e3n = mulnegi(e3);
        // position p = 4*(q*256+tid)+r  <->  bin k = kbase + r*512
        int kbase = ((tid & 7) << 6) | (((tid >> 3) & 7) << 3) | (q << 2) | (tid >> 6);
        zz[AD(kbase)]        = cadd(e0, e2);
        zz[AD(kbase + 1024)] = csub(e0, e2);
        zz[AD(kbase +  512)] = cadd(e1, e3n);   // e1 - i*e3
        zz[AD(kbase + 1536)] = csub(e1, e3n);   // e1 + i*e3
    }
    __syncthreads();

    // conjugate-pair magnitudes: k in [1,1024]; |X[k]|^2 = |A+WB|^2,
    // |X[2048-k]|^2 = |A-WB|^2 from ONE read pair (Y[k], Y[2048-k]).
    unsigned long long keys[8];
#pragma unroll
    for (int j = 0; j < 4; ++j) {
        int k  = 1 + tid + (j << 8);      // 1..1024
        int kp = N2 - k;                  // 1024..2047
        float2 yk = zz[AD(k)];
        float2 yp = zz[AD(kp)];
        float Ar = 0.5f * (yk.x + yp.x), Ai = 0.5f * (yk.y - yp.y);
        float Br = 0.5f * (yk.y + yp.y), Bi = -0.5f * (yk.x - yp.x);
        float2 t = twf[k];                // lane-stride 8 B: coalesced
        float Cr = t.x * Br - t.y * Bi;
        float Ci = t.x * Bi + t.y * Br;
        float m1 = (Ar + Cr) * (Ar + Cr) + (Ai + Ci) * (Ai + Ci);
        float m2 = (Ar - Cr) * (Ar - Cr) + (Ai - Ci) * (Ai - Ci);
        keys[2 * j]     = packkey32(m1, k);
        keys[2 * j + 1] = (kp != k) ? packkey32(m2, kp) : 0ULL;
    }

    // ---- per-thread descending sort (Batcher 8-element network, 19 CEs)
    CSWAP(0,1) CSWAP(2,3) CSWAP(4,5) CSWAP(6,7)
    CSWAP(0,2) CSWAP(1,3) CSWAP(4,6) CSWAP(5,7)
    CSWAP(1,2) CSWAP(5,6)
    CSWAP(0,4) CSWAP(1,5) CSWAP(2,6) CSWAP(3,7)
    CSWAP(2,4) CSWAP(3,5)
    CSWAP(1,2) CSWAP(3,4) CSWAP(5,6)

    const int wv = tid >> 6, ln = tid & 63;
    unsigned long long lb = keys[0];

    // level 1: per-wave top-7; 32-bit max-butterfly on the mag word + ballot
    // winner-resolve; exact-mag ties fall to a rare uniform branch.
    for (int it = 0; it < TOPK; ++it) {
        unsigned int hl = (unsigned int)(lb >> 32);
        unsigned int h  = hl;
#pragma unroll
        for (int off = 32; off; off >>= 1) {
            unsigned int o = __shfl_xor(h, off);
            h = (o > h) ? o : h;
        }
        unsigned long long mask = __ballot(hl == h);
        unsigned long long v;
        if (__popcll(mask) == 1) {
            int src = __ffsll((long long)mask) - 1;
            v = ((unsigned long long)h << 32)
              | (unsigned long long)__shfl((unsigned int)lb, src);
        } else {
            unsigned int l = (hl == h) ? (unsigned int)lb : 0u;
#pragma unroll
            for (int off = 32; off; off >>= 1) {
                unsigned int o = __shfl_xor(l, off);
                l = (o > l) ? o : l;
            }
            v = ((unsigned long long)h << 32) | l;
        }
        if (ln == 0) wavetop[wv * TOPK + it] = v;
        if (v == lb && v) {
            keys[0]=keys[1]; keys[1]=keys[2]; keys[2]=keys[3]; keys[3]=keys[4];
            keys[4]=keys[5]; keys[5]=keys[6]; keys[6]=keys[7]; keys[7]=0ULL;
            lb = keys[0];
        }
    }
    __syncthreads();

    // level 2: merge 28 candidates on one wave (offs <=16 keep lanes <32)
    if (tid < 32) {
        unsigned long long v = (tid < 4 * TOPK) ? wavetop[tid] : 0ULL;
        for (int it = 0; it < TOPK; ++it) {
            unsigned long long m = v;
#pragma unroll
            for (int off = 16; off; off >>= 1) {
                unsigned long long o = __shfl_xor(m, off);
                if (o > m) m = o;
            }
            if (tid == 0) selkey[it] = m;
            if (m == v) v = 0ULL;
        }
    }
    __syncthreads();

    // emit: out = a*cos(theta)+b*sin(theta), theta = 2*pi*k*n/T
    // a = 4*Re/T, b = -4*Im/T; wr + i*wi = e^{+i*2*pi*k/T}.
    if (tid < TOPK) {
        int k  = 2047 - (int)(selkey[tid] & 2047ULL);
        float2 ykf = zz[AD(k)];
        float2 ypf = zz[AD(N2 - k)];
        double ykx = (double)ykf.x, yky = (double)ykf.y;
        double ypx = (double)ypf.x, ypy = (double)ypf.y;
        double Ar = 0.5 * (ykx + ypx), Ai = 0.5 * (yky - ypy);
        double Br = 0.5 * (yky + ypy), Bi = -0.5 * (ykx - ypx);
        double2 t = tw[k];
        double Xr = Ar + t.x * Br - t.y * Bi;
        double Xi = Ai + t.x * Bi + t.y * Br;
        k_out[tid * 4096 + bc] = k;
        ab4[tid * 4096 + bc] = make_float4(
            (float)( 4.0 * Xr / (double)T_LEN),
            (float)(-4.0 * Xi / (double)T_LEN),
            (float)t.x, (float)(-t.y));
    }
}

// ---------------- K2: reconstruction via per-frequency rotators --------------
// block = 256 threads (one per channel), grid = 16 b * 128 n-chunks of 32.
// Output staged in LDS 16n x 256c subtiles -> contiguous nontemporal float4.
__global__ __launch_bounds__(256) void recon_kernel(
    const int* __restrict__ k_in, const float4* __restrict__ ab4,
    float* __restrict__ out)
{
    __shared__ float tile[16][256];

    const int tid   = threadIdx.x;        // channel c
    const int chunk = blockIdx.x & 127;
    const int b     = blockIdx.x >> 7;
    const int bc    = (b << 8) + tid;
    const int n0    = chunk << 5;         // 32 time steps per block

    const float c0 = 6.28318530717958647692f / 4096.0f;
    float aa[TOPK], bb[TOPK];
    c32 z[TOPK], w[TOPK];
#pragma unroll
    for (int j = 0; j < TOPK; ++j) {
        int k    = k_in[j * 4096 + bc];
        float4 v = ab4[j * 4096 + bc];
        aa[j] = v.x; bb[j] = v.y; w[j] = make_float2(v.z, v.w);
        int m0 = (k * n0) & (T_LEN - 1);      // exact integer phase reduction
        float ang = (float)m0 * c0;
        __sincosf(ang, &z[j].y, &z[j].x);
    }

    float* obase = out + ((size_t)b * T_LEN + n0) * NCH;
    for (int r = 0; r < 2; ++r) {             // 2 subtiles of 16 n
#pragma unroll
        for (int i = 0; i < 16; ++i) {
            float acc = 0.f;
#pragma unroll
            for (int j = 0; j < TOPK; ++j) {
                acc += aa[j] * z[j].x + bb[j] * z[j].y;
                z[j] = cmul(z[j], w[j]);
            }
            tile[i][tid] = acc;
        }
        __syncthreads();
        // 1024 float4s per subtile, 4 per thread, contiguous per wave
#pragma unroll
        for (int s = 0; s < 4; ++s) {
            int fid = tid + (s << 8);
            int ni  = fid >> 6;
            int c4  = (fid & 63) << 2;
            nt_f4 v = { tile[ni][c4], tile[ni][c4 + 1],
                        tile[ni][c4 + 2], tile[ni][c4 + 3] };
            __builtin_nontemporal_store(v,
                (nt_f4*)(obase + (size_t)((r << 4) + ni) * NCH + c4));
        }
        __syncthreads();
    }
}

// ---------------- launch -----------------------------------------------------
extern "C" void kernel_launch(void* const* d_in, const int* in_sizes, int n_in,
                              void* d_out, int out_size, void* d_ws, size_t ws_size,
                              hipStream_t stream) {
    const float* x   = (const float*)d_in[0];
    float*       out = (float*)d_out;
    char*        ws  = (char*)d_ws;

    // ws layout: [0, 65536)            tw   double2[4096]
    //            [65536, +114688)      k    int[7][4096]
    //            [180224, +458752)     ab4  float4[7][4096]
    //            [638976, +32768)      twf  float2[4096]
    double2* tw    = (double2*)(ws);
    int*     k_ws  = (int*)   (ws + 65536);
    float4*  ab_ws = (float4*)(ws + 180224);
    float2*  twf   = (float2*)(ws + 638976);

    // d_out doubles as the phase-1 spectrum scratch gz (exactly 64 MB:
    // 4096 cols x 2048 complex f32); recon_kernel overwrites every element
    // of it last, so validation sees only the output.
    prep_kernel     <<<16 + 2048, 256, 0, stream>>>(x, (float2*)out, tw, twf);
    fft_topk_kernel <<<4096, 256, 0, stream>>>(out, tw, twf, k_ws, ab_ws);
    recon_kernel    <<<2048, 256, 0, stream>>>(k_ws, ab_ws, out);
}

// Round 9
// 168.404 us; speedup vs baseline: 1.0376x; 1.0106x over previous
//
#include <hip/hip_runtime.h>
#include <math.h>

#define T_LEN 4096   // time length (FFT size)
#define N2    2048   // packed complex FFT size
#define TOPK  7      // int(ln(2047)) = 7
#define NCH   256    // channels (d)
#define R8F 0.70710678f              // sqrt(2)/2 in f32

// LDS slot map for interleaved complex storage (fft kernel).
// AD(a) = a + (a>>3) + (a>>8): conflict-floor access for every phase pattern.
#define AD(a) ((a) + ((a) >> 3) + ((a) >> 8))

// native clang vector type: required by __builtin_nontemporal_load/store.
typedef float nt_f4 __attribute__((ext_vector_type(4)));

// complex f32 helpers structured for v_pk_add_f32 / v_pk_fma_f32 SLP packing.
typedef float2 c32;
__device__ __forceinline__ c32 cadd(c32 a, c32 b) { return make_float2(a.x + b.x, a.y + b.y); }
__device__ __forceinline__ c32 csub(c32 a, c32 b) { return make_float2(a.x - b.x, a.y - b.y); }
__device__ __forceinline__ c32 cmul(c32 a, c32 w) {
    return make_float2(w.x * a.x - w.y * a.y, w.x * a.y + w.y * a.x);
}
__device__ __forceinline__ c32 csq(c32 a) {
    return make_float2(a.x * a.x - a.y * a.y, 2.0f * a.x * a.y);
}
__device__ __forceinline__ c32 mulnegi(c32 a) { return make_float2(a.y, -a.x); }  // a * (-i)

// radix-8 DIF butterfly network (no twiddles)
__device__ __forceinline__ void dft8_core(c32 x[8])
{
    c32 t0 = cadd(x[0], x[4]), t4 = csub(x[0], x[4]);
    c32 t1 = cadd(x[1], x[5]), t5 = csub(x[1], x[5]);
    c32 t2 = cadd(x[2], x[6]), t6 = csub(x[2], x[6]);
    c32 t3 = cadd(x[3], x[7]), t7 = csub(x[3], x[7]);
    c32 s0 = cadd(t0, t2), s2 = csub(t0, t2);
    c32 s1 = cadd(t1, t3), s3 = csub(t1, t3);
    x[0] = cadd(s0, s1);
    x[4] = csub(s0, s1);
    c32 s3n = mulnegi(s3);
    x[2] = cadd(s2, s3n);                  // s2 - i*s3
    x[6] = csub(s2, s3n);                  // s2 + i*s3
    c32 c1 = make_float2(R8F * (t5.x + t5.y), R8F * (t5.y - t5.x));
    c32 c2 = mulnegi(t6);
    c32 c3 = make_float2(R8F * (t7.y - t7.x), -R8F * (t7.x + t7.y));
    c32 d0 = cadd(t4, c2), d1 = csub(t4, c2);
    c32 d2 = cadd(c1, c3), d3 = csub(c1, c3);
    x[1] = cadd(d0, d2);
    x[5] = csub(d0, d2);
    c32 d3n = mulnegi(d3);
    x[3] = cadd(d1, d3n);                  // d1 - i*d3
    x[7] = csub(d1, d3n);                  // d1 + i*d3
}

// single-column radix-8 with in-register twiddle powers (prep kernel)
__device__ __forceinline__ void dft8_pw(c32 x[8], c32 w1)
{
    dft8_core(x);
    c32 w2 = csq(w1);
    c32 w3 = cmul(w1, w2);
    c32 w4 = csq(w2);
    c32 w5 = cmul(w3, w2);
    c32 w6 = csq(w3);
    c32 w7 = cmul(w4, w3);
    x[1] = cmul(x[1], w1);
    x[2] = cmul(x[2], w2);
    x[3] = cmul(x[3], w3);
    x[4] = cmul(x[4], w4);
    x[5] = cmul(x[5], w5);
    x[6] = cmul(x[6], w6);
    x[7] = cmul(x[7], w7);
}

// TWO independent columns, twiddle powers computed once (fft kernel ILP core):
// the two butterfly networks + 14 cmuls interleave freely in the scheduler,
// filling each wave's dependency-stall shadows.
__device__ __forceinline__ void dft8_pw2(c32 xa[8], c32 xb[8], c32 w1)
{
    dft8_core(xa);
    dft8_core(xb);
    c32 w2 = csq(w1);
    c32 w3 = cmul(w1, w2);
    c32 w4 = csq(w2);
    c32 w5 = cmul(w3, w2);
    c32 w6 = csq(w3);
    c32 w7 = cmul(w4, w3);
    xa[1] = cmul(xa[1], w1); xb[1] = cmul(xb[1], w1);
    xa[2] = cmul(xa[2], w2); xb[2] = cmul(xb[2], w2);
    xa[3] = cmul(xa[3], w3); xb[3] = cmul(xb[3], w3);
    xa[4] = cmul(xa[4], w4); xb[4] = cmul(xb[4], w4);
    xa[5] = cmul(xa[5], w5); xb[5] = cmul(xb[5], w5);
    xa[6] = cmul(xa[6], w6); xb[6] = cmul(xb[6], w6);
    xa[7] = cmul(xa[7], w7); xb[7] = cmul(xb[7], w7);
}

// ---------------- K0: twiddle tables + transpose FUSED WITH FFT PHASE 1 ------
// (unchanged from r8: hardware __sincosf for w1; see r7 post-mortem)
__global__ __launch_bounds__(256) void prep_kernel(
    const float* __restrict__ x, float2* __restrict__ gz,
    double2* __restrict__ tw, float2* __restrict__ twf)
{
    if (blockIdx.x < 16) {
        int p = blockIdx.x * 256 + threadIdx.x;
        double th = -2.0 * 3.14159265358979323846 * (double)p / (double)T_LEN;
        double c = cos(th), s = sin(th);
        tw[p]  = make_double2(c, s);
        twf[p] = make_float2((float)c, (float)s);
        return;
    }
    __shared__ float tile[256][32];       // 32 KB
    const int bid = blockIdx.x - 16;
    const int jt = bid & 15;              // j-tile: j in [16*jt, 16*jt+16)
    const int ct = (bid >> 4) & 7;        // c-tile: c in [32*ct, 32*ct+32)
    const int b  = bid >> 7;
    const int j0 = jt << 4, c0 = ct << 5;
    const int tid = threadIdx.x;

    // load: 256 rows (t = 2*j0 + 512u + rr, u=0..7, rr=0..31) x 32 channels
    const float* src = x + (size_t)b * T_LEN * NCH + c0;
#pragma unroll
    for (int s = 0; s < 8; ++s) {
        int fid = tid + (s << 8);
        int lr  = fid >> 3;               // 0..255
        int qc  = (fid & 7) << 2;         // 0,4,..,28
        int t   = (j0 << 1) + ((lr >> 5) << 9) + (lr & 31);
        nt_f4 v = __builtin_nontemporal_load(
            (const nt_f4*)(src + (size_t)t * NCH + qc));
        int sc = qc ^ ((((lr & 7) ^ ((lr >> 3) & 7))) << 2);
        *(nt_f4*)&tile[lr][sc] = v;       // 16B-aligned (sc multiple of 4)
    }
    __syncthreads();

    // compute: thread handles ONE j (dj = tid&15) and TWO channels (h=0,1).
    const int dj = tid & 15;
    const int j  = j0 + dj;
    // w1 = e^{-i*pi*j/1024}; |ang| < 0.79 so f32 reduction is exact
    float ang = (float)j * -0.00306796157577128218f;   // -pi/1024
    float s1v, c1v;
    __sincosf(ang, &s1v, &c1v);
    c32 w1 = make_float2(c1v, s1v);

    for (int h = 0; h < 2; ++h) {
        const int cc = (tid >> 4) + (h << 4);   // 0..31
        c32 xx[8];
#pragma unroll
        for (int u = 0; u < 8; ++u) {
            int lr0 = (u << 5) + (dj << 1);     // y[j+256u] = x[2j+512u] + i*x[..+1]
            int lr1 = lr0 + 1;
            int s0  = cc ^ ((((lr0 & 7) ^ ((lr0 >> 3) & 7))) << 2);
            int s1  = cc ^ ((((lr1 & 7) ^ ((lr1 >> 3) & 7))) << 2);
            xx[u] = make_float2(tile[lr0][s0], tile[lr1][s1]);
        }
        dft8_pw(xx, w1);                         // phase-1 twiddle base = 2j
        float2* gcol = gz + ((size_t)((b << 8) + c0 + cc)) * N2;
#pragma unroll
        for (int m = 0; m < 8; ++m)
            gcol[(m << 8) + j] = xx[m];          // dj-runs of 16 -> 128 B coalesced
    }
}

// pack (f32 magnitude^2 bits, bin) into one monotone u64 key.
__device__ __forceinline__ unsigned long long packkey32(float mag, int k) {
    return ((unsigned long long)__float_as_uint(mag) << 32)
         | (unsigned long long)(2047 - k);
}

// descending compare-swap for the per-thread sorting network
#define CSWAP(K, i, j) { unsigned long long a_ = K[i], b_ = K[j]; \
                         K[i] = a_ > b_ ? a_ : b_; K[j] = a_ > b_ ? b_ : a_; }
#define SORT8(K) \
    CSWAP(K,0,1) CSWAP(K,2,3) CSWAP(K,4,5) CSWAP(K,6,7) \
    CSWAP(K,0,2) CSWAP(K,1,3) CSWAP(K,4,6) CSWAP(K,5,7) \
    CSWAP(K,1,2) CSWAP(K,5,6) \
    CSWAP(K,0,4) CSWAP(K,1,5) CSWAP(K,2,6) CSWAP(K,3,7) \
    CSWAP(K,2,4) CSWAP(K,3,5) \
    CSWAP(K,1,2) CSWAP(K,3,4) CSWAP(K,5,6)

// one level-1 selection round for one column: 32-bit max-butterfly on the mag
// word + ballot winner-resolve; exact-mag ties in a rare uniform branch.
__device__ __forceinline__ void sel_round(
    unsigned long long keys[8], unsigned long long& lb,
    unsigned long long* wavetop, int wv, int ln, int it)
{
    unsigned int hl = (unsigned int)(lb >> 32);
    unsigned int h  = hl;
#pragma unroll
    for (int off = 32; off; off >>= 1) {
        unsigned int o = __shfl_xor(h, off);
        h = (o > h) ? o : h;
    }
    unsigned long long mask = __ballot(hl == h);
    unsigned long long v;
    if (__popcll(mask) == 1) {
        int src = __ffsll((long long)mask) - 1;
        v = ((unsigned long long)h << 32)
          | (unsigned long long)__shfl((unsigned int)lb, src);
    } else {
        unsigned int l = (hl == h) ? (unsigned int)lb : 0u;
#pragma unroll
        for (int off = 32; off; off >>= 1) {
            unsigned int o = __shfl_xor(l, off);
            l = (o > l) ? o : l;
        }
        v = ((unsigned long long)h << 32) | l;
    }
    if (ln == 0) wavetop[wv * TOPK + it] = v;
    if (v == lb && v) {
        keys[0]=keys[1]; keys[1]=keys[2]; keys[2]=keys[3]; keys[3]=keys[4];
        keys[4]=keys[5]; keys[5]=keys[6]; keys[6]=keys[7]; keys[7]=0ULL;
        lb = keys[0];
    }
}

// ---------------- K1: radix-8 real FFT phases 2-4 (f32) + top-7, 2 COLUMNS ---
// One block per column-PAIR (grid 2048). r8 post-mortem: fft issues only ~27%
// of cycles (stall-dominated, not instruction-bound) — so this trades TLP
// (4 blocks/CU instead of 8) for 2x per-wave ILP: every load/butterfly chain
// has an independent twin from the adjacent column, and twiddle power chains
// are computed once for both. Arithmetic per column is bit-identical.
__global__ __launch_bounds__(256, 4) void fft_topk_kernel(
    const float* __restrict__ xt, const double2* __restrict__ tw,
    const float2* __restrict__ twf,
    int* __restrict__ k_out, float4* __restrict__ ab4)
{
    __shared__ float2 zzA[AD(N2 - 1) + 3];           // 18.5 KB
    __shared__ float2 zzB[AD(N2 - 1) + 3];           // 18.5 KB
    __shared__ unsigned long long wavetopA[4 * TOPK], wavetopB[4 * TOPK];
    __shared__ unsigned long long selkeyA[TOPK], selkeyB[TOPK];

    const int tid = threadIdx.x;
    const int bcA = blockIdx.x * 2;      // column pair
    const float2* gA = ((const float2*)xt) + (size_t)bcA * N2;
    const float2* gB = gA + N2;

    c32 xa[8], xb[8];
    // phase 2: sub-FFT size 256, j2 = tid&31, stride 32; tw base 16*j2.
    {
        const int g = tid >> 5, j2 = tid & 31, base = (g << 8) + j2;
#pragma unroll
        for (int u = 0; u < 8; ++u) {
            xa[u] = gA[base + (u << 5)];
            xb[u] = gB[base + (u << 5)];
        }
        dft8_pw2(xa, xb, twf[16 * j2]);
#pragma unroll
        for (int m = 0; m < 8; ++m) {
            int ad = AD(base + (m << 5));
            zzA[ad] = xa[m]; zzB[ad] = xb[m];
        }
    }
    __syncthreads();

    // phase 3: sub-FFT size 32, j3 = tid&3, stride 4; tw base 128*j3.
    {
        const int g3 = tid >> 2, j3 = tid & 3, base = (g3 << 5) + j3;
#pragma unroll
        for (int u = 0; u < 8; ++u) {
            int ad = AD(base + (u << 2));
            xa[u] = zzA[ad]; xb[u] = zzB[ad];
        }
        dft8_pw2(xa, xb, twf[128 * j3]);
#pragma unroll
        for (int m = 0; m < 8; ++m) {
            int ad = AD(base + (m << 2));
            zzA[ad] = xa[m]; zzB[ad] = xb[m];
        }
    }
    __syncthreads();

    // phase 4: read both stride-1 quads (digit-index space), barrier,
    // DFT4 in registers, write natural-order at AD(k).
#pragma unroll
    for (int q = 0; q < 2; ++q) {
        int h4 = ((q << 8) + tid) << 2;
#pragma unroll
        for (int r = 0; r < 4; ++r) {
            int ad = AD(h4 + r);
            xa[q * 4 + r] = zzA[ad]; xb[q * 4 + r] = zzB[ad];
        }
    }
    __syncthreads();
#pragma unroll
    for (int q = 0; q < 2; ++q) {
        // position p = 4*(q*256+tid)+r  <->  bin k = kbase + r*512
        int kbase = ((tid & 7) << 6) | (((tid >> 3) & 7) << 3) | (q << 2) | (tid >> 6);
        {
            c32 b0 = xa[q*4+0], b1 = xa[q*4+1], b2 = xa[q*4+2], b3 = xa[q*4+3];
            c32 e0 = cadd(b0, b2), e1 = csub(b0, b2);
            c32 e2 = cadd(b1, b3), e3 = csub(b1, b3);
            c32 e3n = mulnegi(e3);
            zzA[AD(kbase)]        = cadd(e0, e2);
            zzA[AD(kbase + 1024)] = csub(e0, e2);
            zzA[AD(kbase +  512)] = cadd(e1, e3n);   // e1 - i*e3
            zzA[AD(kbase + 1536)] = csub(e1, e3n);   // e1 + i*e3
        }
        {
            c32 b0 = xb[q*4+0], b1 = xb[q*4+1], b2 = xb[q*4+2], b3 = xb[q*4+3];
            c32 e0 = cadd(b0, b2), e1 = csub(b0, b2);
            c32 e2 = cadd(b1, b3), e3 = csub(b1, b3);
            c32 e3n = mulnegi(e3);
            zzB[AD(kbase)]        = cadd(e0, e2);
            zzB[AD(kbase + 1024)] = csub(e0, e2);
            zzB[AD(kbase +  512)] = cadd(e1, e3n);
            zzB[AD(kbase + 1536)] = csub(e1, e3n);
        }
    }
    __syncthreads();

    // conjugate-pair magnitudes for both columns from shared twf loads.
    unsigned long long keysA[8], keysB[8];
#pragma unroll
    for (int j = 0; j < 4; ++j) {
        int k  = 1 + tid + (j << 8);      // 1..1024
        int kp = N2 - k;                  // 1024..2047
        int adk = AD(k), adp = AD(kp);
        float2 t = twf[k];
        {
            float2 yk = zzA[adk], yp = zzA[adp];
            float Ar = 0.5f * (yk.x + yp.x), Ai = 0.5f * (yk.y - yp.y);
            float Br = 0.5f * (yk.y + yp.y), Bi = -0.5f * (yk.x - yp.x);
            float Cr = t.x * Br - t.y * Bi;
            float Ci = t.x * Bi + t.y * Br;
            float m1 = (Ar + Cr) * (Ar + Cr) + (Ai + Ci) * (Ai + Ci);
            float m2 = (Ar - Cr) * (Ar - Cr) + (Ai - Ci) * (Ai - Ci);
            keysA[2 * j]     = packkey32(m1, k);
            keysA[2 * j + 1] = (kp != k) ? packkey32(m2, kp) : 0ULL;
        }
        {
            float2 yk = zzB[adk], yp = zzB[adp];
            float Ar = 0.5f * (yk.x + yp.x), Ai = 0.5f * (yk.y - yp.y);
            float Br = 0.5f * (yk.y + yp.y), Bi = -0.5f * (yk.x - yp.x);
            float Cr = t.x * Br - t.y * Bi;
            float Ci = t.x * Bi + t.y * Br;
            float m1 = (Ar + Cr) * (Ar + Cr) + (Ai + Ci) * (Ai + Ci);
            float m2 = (Ar - Cr) * (Ar - Cr) + (Ai - Ci) * (Ai - Ci);
            keysB[2 * j]     = packkey32(m1, k);
            keysB[2 * j + 1] = (kp != k) ? packkey32(m2, kp) : 0ULL;
        }
    }

    // per-thread descending sorts (independent -> ILP)
    SORT8(keysA)
    SORT8(keysB)

    const int wv = tid >> 6, ln = tid & 63;
    unsigned long long lbA = keysA[0], lbB = keysB[0];

    // level 1: per-wave top-7 for both columns, rounds interleaved.
    for (int it = 0; it < TOPK; ++it) {
        sel_round(keysA, lbA, wavetopA, wv, ln, it);
        sel_round(keysB, lbB, wavetopB, wv, ln, it);
    }
    __syncthreads();

    // level 2: lanes 0-31 of wave 0 merge A; lanes 32-63 merge B.
    // (__shfl_xor offsets <=16 never cross the 32-lane halves.)
    if (tid < 64) {
        const bool isB = tid >= 32;
        const int  sl  = tid & 31;
        const unsigned long long* wt = isB ? wavetopB : wavetopA;
        unsigned long long* sk = isB ? selkeyB : selkeyA;
        unsigned long long v = (sl < 4 * TOPK) ? wt[sl] : 0ULL;
        for (int it = 0; it < TOPK; ++it) {
            unsigned long long m = v;
#pragma unroll
            for (int off = 16; off; off >>= 1) {
                unsigned long long o = __shfl_xor(m, off);
                if (o > m) m = o;
            }
            if (sl == 0) sk[it] = m;
            if (m == v) v = 0ULL;
        }
    }
    __syncthreads();

    // emit: lanes 0-6 emit column A; lanes 64-70 emit column B.
    if (tid < TOPK || (tid >= 64 && tid < 64 + TOPK)) {
        const bool isB = tid >= 64;
        const int  sl  = isB ? tid - 64 : tid;
        const int  bc  = bcA + (isB ? 1 : 0);
        const float2* zz = isB ? zzB : zzA;
        int k  = 2047 - (int)((isB ? selkeyB[sl] : selkeyA[sl]) & 2047ULL);
        float2 ykf = zz[AD(k)];
        float2 ypf = zz[AD(N2 - k)];
        double ykx = (double)ykf.x, yky = (double)ykf.y;
        double ypx = (double)ypf.x, ypy = (double)ypf.y;
        double Ar = 0.5 * (ykx + ypx), Ai = 0.5 * (yky - ypy);
        double Br = 0.5 * (yky + ypy), Bi = -0.5 * (ykx - ypx);
        double2 t = tw[k];
        double Xr = Ar + t.x * Br - t.y * Bi;
        double Xi = Ai + t.x * Bi + t.y * Br;
        k_out[sl * 4096 + bc] = k;
        ab4[sl * 4096 + bc] = make_float4(
            (float)( 4.0 * Xr / (double)T_LEN),
            (float)(-4.0 * Xi / (double)T_LEN),
            (float)t.x, (float)(-t.y));
    }
}

// ---------------- K2: reconstruction via per-frequency rotators --------------
// block = 256 threads (one per channel), grid = 16 b * 128 n-chunks of 32.
// Output staged in LDS 16n x 256c subtiles -> contiguous nontemporal float4.
__global__ __launch_bounds__(256) void recon_kernel(
    const int* __restrict__ k_in, const float4* __restrict__ ab4,
    float* __restrict__ out)
{
    __shared__ float tile[16][256];

    const int tid   = threadIdx.x;        // channel c
    const int chunk = blockIdx.x & 127;
    const int b     = blockIdx.x >> 7;
    const int bc    = (b << 8) + tid;
    const int n0    = chunk << 5;         // 32 time steps per block

    const float c0 = 6.28318530717958647692f / 4096.0f;
    float aa[TOPK], bb[TOPK];
    c32 z[TOPK], w[TOPK];
#pragma unroll
    for (int j = 0; j < TOPK; ++j) {
        int k    = k_in[j * 4096 + bc];
        float4 v = ab4[j * 4096 + bc];
        aa[j] = v.x; bb[j] = v.y; w[j] = make_float2(v.z, v.w);
        int m0 = (k * n0) & (T_LEN - 1);      // exact integer phase reduction
        float ang = (float)m0 * c0;
        __sincosf(ang, &z[j].y, &z[j].x);
    }

    float* obase = out + ((size_t)b * T_LEN + n0) * NCH;
    for (int r = 0; r < 2; ++r) {             // 2 subtiles of 16 n
#pragma unroll
        for (int i = 0; i < 16; ++i) {
            float acc = 0.f;
#pragma unroll
            for (int j = 0; j < TOPK; ++j) {
                acc += aa[j] * z[j].x + bb[j] * z[j].y;
                z[j] = cmul(z[j], w[j]);
            }
            tile[i][tid] = acc;
        }
        __syncthreads();
        // 1024 float4s per subtile, 4 per thread, contiguous per wave
#pragma unroll
        for (int s = 0; s < 4; ++s) {
            int fid = tid + (s << 8);
            int ni  = fid >> 6;
            int c4  = (fid & 63) << 2;
            nt_f4 v = { tile[ni][c4], tile[ni][c4 + 1],
                        tile[ni][c4 + 2], tile[ni][c4 + 3] };
            __builtin_nontemporal_store(v,
                (nt_f4*)(obase + (size_t)((r << 4) + ni) * NCH + c4));
        }
        __syncthreads();
    }
}

// ---------------- launch -----------------------------------------------------
extern "C" void kernel_launch(void* const* d_in, const int* in_sizes, int n_in,
                              void* d_out, int out_size, void* d_ws, size_t ws_size,
                              hipStream_t stream) {
    const float* x   = (const float*)d_in[0];
    float*       out = (float*)d_out;
    char*        ws  = (char*)d_ws;

    // ws layout: [0, 65536)            tw   double2[4096]
    //            [65536, +114688)      k    int[7][4096]
    //            [180224, +458752)     ab4  float4[7][4096]
    //            [638976, +32768)      twf  float2[4096]
    double2* tw    = (double2*)(ws);
    int*     k_ws  = (int*)   (ws + 65536);
    float4*  ab_ws = (float4*)(ws + 180224);
    float2*  twf   = (float2*)(ws + 638976);

    // d_out doubles as the phase-1 spectrum scratch gz (exactly 64 MB:
    // 4096 cols x 2048 complex f32); recon_kernel overwrites every element
    // of it last, so validation sees only the output.
    prep_kernel     <<<16 + 2048, 256, 0, stream>>>(x, (float2*)out, tw, twf);
    fft_topk_kernel <<<2048, 256, 0, stream>>>(out, tw, twf, k_ws, ab_ws);
    recon_kernel    <<<2048, 256, 0, stream>>>(k_ws, ab_ws, out);
}